// Round 10
// baseline (368.505 us; speedup 1.0000x reference)
//
#include <hip/hip_runtime.h>
#include <math.h>

// VectorQuantizer — bit-exact emulation of the numpy fp32 reference (proven R2-R9):
//   d[n,k] = fl32( fl32(x2[n]+c2[k]) - fl32(2 * fl32(exact_fp64_dot)) ), first argmin.
// R6/R9 (184-190us) are SMEM-bound: codebook via s_load, and the scalar cache's
// shallow miss-handling serializes ALL resident waves (VALUBusy stuck at 33%
// regardless of wave count). R7 showed LDS broadcast floors at ~164us (12cyc/b128
// is per-instruction, broadcast or not). R10: codebook via VMEM same-address
// loads — TA coalesces 64 identical addrs to one L2 request, deep vmcnt queue,
// uncorrelated per-wave stalls -> wave overlap finally works. This is R4/R5's
// accidental path minus their fatal launch_bounds VGPR cap (the spill, not the
// VMEM, was their regression).

#define N_CODES   512
#define CODE_DIM  64
#define CH_STRIDE 4096                      // floats between channels
#define B_STRIDE  (CODE_DIM * CH_STRIDE)    // floats between batches
#define N_GW      1024                      // (b,h) row-groups
#define NWAVE     8                         // waves per block
#define KCHUNK    (N_CODES / NWAVE)         // 64 codes per wave
#define CAP       4                         // candidate buffer per lane

// numpy pairwise_sum for n=64 (loops.c.src) — setup kernel only.
__device__ __forceinline__ float np_pairwise_sum64(const float* a) {
    float r[8];
#pragma unroll
    for (int j = 0; j < 8; ++j) r[j] = a[j];
#pragma unroll
    for (int i = 8; i < 64; i += 8) {
#pragma unroll
        for (int j = 0; j < 8; ++j) r[j] = __fadd_rn(r[j], a[i + j]);
    }
    return __fadd_rn(__fadd_rn(__fadd_rn(r[0], r[1]), __fadd_rn(r[2], r[3])),
                     __fadd_rn(__fadd_rn(r[4], r[5]), __fadd_rn(r[6], r[7])));
}

__global__ void vq_setup_kernel(const float* __restrict__ cb, float* __restrict__ c2) {
    const int k = blockIdx.x * blockDim.x + threadIdx.x;
    if (k < N_CODES) {
        const float* row = cb + k * CODE_DIM;
        float sq[CODE_DIM];
#pragma unroll
        for (int j = 0; j < CODE_DIM; ++j) sq[j] = __fmul_rn(row[j], row[j]);
        c2[k] = np_pairwise_sum64(sq);
    }
}

// Exact dk — identical arithmetic to the R2 kernel that passed.
__device__ __forceinline__ float exact_dk(const float* __restrict__ cb,
                                          const float* __restrict__ c2,
                                          const float (&x)[CODE_DIM], float x2, int k) {
    const float* crow = cb + (size_t)k * CODE_DIM;
    double a0 = 0.0, a1 = 0.0, a2 = 0.0, a3 = 0.0;
#pragma unroll
    for (int j = 0; j < CODE_DIM; j += 4) {
        a0 = fma((double)crow[j + 0], (double)x[j + 0], a0);
        a1 = fma((double)crow[j + 1], (double)x[j + 1], a1);
        a2 = fma((double)crow[j + 2], (double)x[j + 2], a2);
        a3 = fma((double)crow[j + 3], (double)x[j + 3], a3);
    }
    const double dot = (a0 + a1) + (a2 + a3);
    const float  ein = (float)dot;
    const float  tmp = __fadd_rn(x2, c2[k]);
    return __fsub_rn(tmp, __fmul_rn(2.0f, ein));
}

// One block per (b,h), 8 waves. lane = w (coalesced 256B channel loads). Wave wid
// scans codes [k0, k0+64); codebook rows via same-address VMEM float4 loads.
__global__ __launch_bounds__(512)
void vq_main_kernel(const float* __restrict__ in,
                    const float* __restrict__ cb,
                    const float* __restrict__ c2,
                    float* __restrict__ out) {
    __shared__ float s_cdk[CAP][512];   // [entry][thread]: conflict-free, 8 KB
    __shared__ int   s_cki[CAP][512];   // 8 KB
    __shared__ float s_rb[NWAVE][64];   // per-wave chunk winner dk, 2 KB
    __shared__ int   s_ri[NWAVE][64];   // per-wave chunk winner k,  2 KB

    const int tid  = threadIdx.x;
    const int lane = tid & 63;
    const int wid  = tid >> 6;          // 0..7 -> k-chunk
    const int gw   = blockIdx.x;        // 0..1023
    const int b    = gw >> 6;
    const int h    = gw & 63;

    // x[0..63] in VGPRs (stride-4096 loads, coalesced across lanes).
    const float* xin = in + (size_t)b * B_STRIDE + (size_t)h * 64 + lane;
    float x[CODE_DIM];
#pragma unroll
    for (int c = 0; c < CODE_DIM; ++c) x[c] = xin[(size_t)c * CH_STRIDE];

    // x2 = np.sum(x*x) in numpy pairwise order, rolling 8 accumulators (R5-proven).
    float r[8];
#pragma unroll
    for (int j = 0; j < 8; ++j) r[j] = __fmul_rn(x[j], x[j]);
#pragma unroll
    for (int i = 8; i < 64; i += 8) {
#pragma unroll
        for (int j = 0; j < 8; ++j)
            r[j] = __fadd_rn(r[j], __fmul_rn(x[i + j], x[i + j]));
    }
    const float x2 = __fadd_rn(
        __fadd_rn(__fadd_rn(r[0], r[1]), __fadd_rn(r[2], r[3])),
        __fadd_rn(__fadd_rn(r[4], r[5]), __fadd_rn(r[6], r[7])));

    // Plain (compiler-divergent) k0 -> codebook loads go through VMEM, not SMEM.
    const int k0 = wid * KCHUNK;

    // --- Pass 1: fp32 fast scan of this wave's 64-code chunk -----------------
    // Capture any k with dk_fast <= chunk_best + thr, thr = 4.5*ulp(best)+8e-6
    // (>= 2*(fast-scan error) incl. binade edge) => exact chunk argmin captured.
    float best = INFINITY, cut = INFINITY;
    int   count = 0, overflow = 0;

#pragma unroll 1
    for (int kk = 0; kk < KCHUNK; ++kk) {
        const int k = k0 + kk;
        const float4* crow4 = (const float4*)(cb + (size_t)k * CODE_DIM);
        float a0 = 0.f, a1 = 0.f, a2 = 0.f, a3 = 0.f;
#pragma unroll
        for (int jj = 0; jj < 16; ++jj) {
            const float4 v = crow4[jj];       // same addr across lanes -> 1 req
            a0 = fmaf(x[4 * jj + 0], v.x, a0);
            a1 = fmaf(x[4 * jj + 1], v.y, a1);
            a2 = fmaf(x[4 * jj + 2], v.z, a2);
            a3 = fmaf(x[4 * jj + 3], v.w, a3);
        }
        const float dot = __fadd_rn(__fadd_rn(a0, a1), __fadd_rn(a2, a3));
        const float dk  = __fsub_rn(__fadd_rn(x2, c2[k]), __fmul_rn(2.0f, dot));

        const bool ins = (dk <= cut);   // old cut: conservative superset
        if (dk < best) {
            best = dk;
            const float g = __uint_as_float(__float_as_uint(best) & 0xFF800000u)
                            * 1.1920929e-7f;          // ulp(best)
            cut = __fadd_rn(best, __fmaf_rn(4.5f, g, 8e-6f));
        }
        if (ins) {
            if (count == CAP) {         // compact: drop entries above current cut
                int nc = 0;
#pragma unroll 1
                for (int i = 0; i < CAP; ++i) {
                    const float d  = s_cdk[i][tid];
                    const int   ki = s_cki[i][tid];
                    if (d <= cut) { s_cdk[nc][tid] = d; s_cki[nc][tid] = ki; ++nc; }
                }
                count = nc;
            }
            if (count < CAP) {
                s_cdk[count][tid] = dk;
                s_cki[count][tid] = k;
                ++count;
            } else {
                overflow = 1;
            }
        }
    }

    // --- Pass 2: exact re-resolution of this chunk's candidates --------------
    float ex_best = INFINITY;
    int   bi = k0;
#pragma unroll 1
    for (int i = 0; i < count; ++i) {
        const int   k  = s_cki[i][tid];
        const float dk = exact_dk(cb, c2, x, x2, k);
        if (dk < ex_best) { ex_best = dk; bi = k; }   // ascending k => first-min
    }
    if (__builtin_amdgcn_ballot_w64(overflow != 0)) { // ~never: exact rescan of chunk
        if (overflow) {
            ex_best = INFINITY; bi = k0;
#pragma unroll 1
            for (int kk = 0; kk < KCHUNK; ++kk) {
                const float dk = exact_dk(cb, c2, x, x2, k0 + kk);
                if (dk < ex_best) { ex_best = dk; bi = k0 + kk; }
            }
        }
    }

    // --- Combine the 8 chunk winners (min dk; ties -> lower chunk => lower k) -
    s_rb[wid][lane] = ex_best;
    s_ri[wid][lane] = bi;
    __syncthreads();
    float fb = s_rb[0][lane];
    int   fi = s_ri[0][lane];
#pragma unroll
    for (int w = 1; w < NWAVE; ++w) {
        const float d  = s_rb[w][lane];
        const int   i2 = s_ri[w][lane];
        if (d < fb) { fb = d; fi = i2; }   // strict < keeps earliest chunk on ties
    }

    // --- Output: each wave writes 8 of the 64 rows (coalesced 256B each) -----
    const size_t n0 = (size_t)gw * 64;
#pragma unroll 1
    for (int rr = 0; rr < 8; ++rr) {
        const int row  = wid * 8 + rr;
        const int idxr = __shfl(fi, row, 64);
        out[(n0 + row) * CODE_DIM + lane] = cb[(size_t)idxr * CODE_DIM + lane];
    }
}

extern "C" void kernel_launch(void* const* d_in, const int* in_sizes, int n_in,
                              void* d_out, int out_size, void* d_ws, size_t ws_size,
                              hipStream_t stream) {
    const float* in  = (const float*)d_in[0];   // (16,64,64,64) fp32
    const float* cb  = (const float*)d_in[1];   // (512,64) fp32
    float*       out = (float*)d_out;           // (16,64,64,64) fp32
    float*       c2  = (float*)d_ws;            // 512 floats scratch

    vq_setup_kernel<<<dim3(2), dim3(256), 0, stream>>>(cb, c2);
    vq_main_kernel<<<dim3(N_GW), dim3(512), 0, stream>>>(in, cb, c2, out);
}

// Round 11
// 230.843 us; speedup vs baseline: 1.5963x; 1.5963x over previous
//
#include <hip/hip_runtime.h>
#include <math.h>

// VectorQuantizer — bit-exact emulation of the numpy fp32 reference (proven R2-R10):
//   d[n,k] = fl32( fl32(x2[n]+c2[k]) - fl32(2 * fl32(exact_fp64_dot)) ), first argmin.
// R3-R10 mapped the broadcast-codebook design space: SMEM s_load 184us, LDS
// broadcast 220us, VMEM broadcast 322us — all bound by feeding a wave-uniform
// operand. R11 removes the broadcast: classic GEMM register tiling. Block =
// 16 rows x 512 codes; lane owns a 4x8 accumulator tile; per dim: 1 ds_read_b128
// (x-frag from 5KB LDS tile) + 2 coalesced global dwordx4 (c-frag from a
// pre-transposed cbT[dim][code] in ws, L2-resident) feeding 32 FMAs -> VALU-bound.
// All 512 codes in-block => block-local selection; near-best cells re-resolved
// with the bit-identical R2 fp64 formula; (dk,k)-packed LDS u64 atomicMin gives
// the reference first-argmin.

#define N_CODES   512
#define CODE_DIM  64
#define CH_STRIDE 4096                      // floats between channels
#define B_STRIDE  (CODE_DIM * CH_STRIDE)    // floats between batches
#define RPB       16                        // rows per block
#define XPITCH    20                        // xs pitch (mult of 4 -> b128-aligned)
#define THR       1.2e-4f                   // >= 2*(dk-formula rounding + fast-dot err)

// ---------------- setup: c2 (numpy pairwise) + cbT transpose ----------------
__device__ __forceinline__ float np_pairwise_sum64(const float* a) {
    float r[8];
#pragma unroll
    for (int j = 0; j < 8; ++j) r[j] = a[j];
#pragma unroll
    for (int i = 8; i < 64; i += 8) {
#pragma unroll
        for (int j = 0; j < 8; ++j) r[j] = __fadd_rn(r[j], a[i + j]);
    }
    return __fadd_rn(__fadd_rn(__fadd_rn(r[0], r[1]), __fadd_rn(r[2], r[3])),
                     __fadd_rn(__fadd_rn(r[4], r[5]), __fadd_rn(r[6], r[7])));
}

__global__ void vq_setup_kernel(const float* __restrict__ cb, float* __restrict__ c2,
                                float* __restrict__ cbT, int buildT) {
    const int t = blockIdx.x * blockDim.x + threadIdx.x;   // 64 blocks x 512
    if (buildT && t < N_CODES * CODE_DIM) {
        const int j = t >> 9, k = t & 511;                 // cbT[j][k] = cb[k][j]
        cbT[(j << 9) | k] = cb[k * CODE_DIM + j];
    }
    if (t < N_CODES) {
        const float* row = cb + t * CODE_DIM;
        float sq[CODE_DIM];
#pragma unroll
        for (int j = 0; j < CODE_DIM; ++j) sq[j] = __fmul_rn(row[j], row[j]);
        c2[t] = np_pairwise_sum64(sq);
    }
}

// ---------------- main: GEMM-tiled scan + exact resolve ---------------------
__global__ __launch_bounds__(256)
void vq_gemm_kernel(const float* __restrict__ in,
                    const float* __restrict__ cb,
                    const float* __restrict__ c2g,
                    const float* __restrict__ cbT,
                    float* __restrict__ out) {
    __shared__ __align__(16) float xs[CODE_DIM][XPITCH];   // x-tile [dim][row], 5KB
    __shared__ float s_wm[4][RPB];                         // per-wave row mins
    __shared__ float s_bmin[RPB];
    __shared__ float s_x2e[RPB];                           // numpy-exact x2 per row
    __shared__ unsigned long long s_res[RPB];              // packed (dk,k)

    const int tid  = threadIdx.x;
    const int lane = tid & 63;
    const int wid  = tid >> 6;              // 0..3
    const int gw   = blockIdx.x >> 2;       // (b,h) group 0..1023
    const int w0   = (blockIdx.x & 3) * RPB;

    const float* src = in + (size_t)(gw >> 6) * B_STRIDE + (size_t)(gw & 63) * 64;

    // --- stage x-tile: xs[c][r] = src[c*4096 + w0 + r]; 4 values per thread ---
    {
        const int r  = tid & 15;
        const int c0 = (tid >> 4) * 4;
#pragma unroll
        for (int i = 0; i < 4; ++i)
            xs[c0 + i][r] = src[(size_t)(c0 + i) * CH_STRIDE + w0 + r];
    }
    if (tid < RPB) s_res[tid] = ~0ull;
    __syncthreads();

    // --- numpy-exact x2 per row (R5-proven rolling 8-acc pairwise order) -----
    if (tid < RPB) {
        float r[8];
#pragma unroll
        for (int j = 0; j < 8; ++j) r[j] = __fmul_rn(xs[j][tid], xs[j][tid]);
#pragma unroll
        for (int i = 8; i < 64; i += 8) {
#pragma unroll
            for (int j = 0; j < 8; ++j)
                r[j] = __fadd_rn(r[j], __fmul_rn(xs[i + j][tid], xs[i + j][tid]));
        }
        s_x2e[tid] = __fadd_rn(
            __fadd_rn(__fadd_rn(r[0], r[1]), __fadd_rn(r[2], r[3])),
            __fadd_rn(__fadd_rn(r[4], r[5]), __fadd_rn(r[6], r[7])));
    }

    // --- lane tile: rows r0..r0+3, codes code0..code0+7 ----------------------
    const int r0    = (lane & 3) * 4;
    const int code0 = wid * 128 + (lane >> 2) * 8;

    float acc[4][8];
#pragma unroll
    for (int r = 0; r < 4; ++r)
#pragma unroll
        for (int j = 0; j < 8; ++j) acc[r][j] = 0.f;

    // --- hot loop: per dim 1 LDS b128 + 2 coalesced global dwordx4 -> 32 FMA --
    const float* cbTw = cbT + code0;
#pragma unroll 4
    for (int c = 0; c < CODE_DIM; ++c) {
        const float4 xv  = *(const float4*)&xs[c][r0];
        const float4 ca  = *(const float4*)(cbTw + (size_t)c * N_CODES);
        const float4 cb4 = *(const float4*)(cbTw + (size_t)c * N_CODES + 4);
        const float xr[4] = {xv.x, xv.y, xv.z, xv.w};
        const float cv[8] = {ca.x, ca.y, ca.z, ca.w, cb4.x, cb4.y, cb4.z, cb4.w};
#pragma unroll
        for (int r = 0; r < 4; ++r)
#pragma unroll
            for (int j = 0; j < 8; ++j)
                acc[r][j] = fmaf(xr[r], cv[j], acc[r][j]);
    }

    // ek = c2[k] - 2*dot  (x2 shift is argmin-invariant within a row)
    float c2v[8];
    {
        const float4 a = *(const float4*)(c2g + code0);
        const float4 b = *(const float4*)(c2g + code0 + 4);
        c2v[0] = a.x; c2v[1] = a.y; c2v[2] = a.z; c2v[3] = a.w;
        c2v[4] = b.x; c2v[5] = b.y; c2v[6] = b.z; c2v[7] = b.w;
    }
#pragma unroll
    for (int r = 0; r < 4; ++r)
#pragma unroll
        for (int j = 0; j < 8; ++j)
            acc[r][j] = __fmaf_rn(-2.0f, acc[r][j], c2v[j]);

    // --- per-row fast min: lane tile -> shuffle over lanes sharing row-group --
    float m[4];
#pragma unroll
    for (int r = 0; r < 4; ++r) {
        float mm = acc[r][0];
#pragma unroll
        for (int j = 1; j < 8; ++j) mm = fminf(mm, acc[r][j]);
        m[r] = mm;
    }
#pragma unroll
    for (int s = 4; s < 64; s <<= 1) {
#pragma unroll
        for (int r = 0; r < 4; ++r) m[r] = fminf(m[r], __shfl_xor(m[r], s, 64));
    }
    if (lane < 4) {
#pragma unroll
        for (int r = 0; r < 4; ++r) s_wm[wid][lane * 4 + r] = m[r];
        // note: lane == its own row-group here (lane&3 == lane)
    }
    __syncthreads();
    if (tid < RPB) {
        float bm = s_wm[0][tid];
#pragma unroll
        for (int w = 1; w < 4; ++w) bm = fminf(bm, s_wm[w][tid]);
        s_bmin[tid] = bm;
    }
    __syncthreads();

    // --- exact resolve of near-best cells (bit-identical R2 arithmetic) ------
#pragma unroll 1
    for (int r = 0; r < 4; ++r) {
        const int row = r0 + r;
        const float lim = s_bmin[row] + THR;
#pragma unroll 1
        for (int j = 0; j < 8; ++j) {
            if (acc[r][j] <= lim) {
                const int k = code0 + j;
                const float* crow = cb + (size_t)k * CODE_DIM;
                double b0 = 0.0, b1 = 0.0, b2 = 0.0, b3 = 0.0;
#pragma unroll
                for (int c = 0; c < CODE_DIM; c += 4) {
                    b0 = fma((double)crow[c + 0], (double)xs[c + 0][row], b0);
                    b1 = fma((double)crow[c + 1], (double)xs[c + 1][row], b1);
                    b2 = fma((double)crow[c + 2], (double)xs[c + 2][row], b2);
                    b3 = fma((double)crow[c + 3], (double)xs[c + 3][row], b3);
                }
                const double dot64 = (b0 + b1) + (b2 + b3);
                const float  ein   = (float)dot64;
                const float  tmp   = __fadd_rn(s_x2e[row], c2g[k]);
                const float  dk    = __fsub_rn(tmp, __fmul_rn(2.0f, ein));
                const unsigned u   = __float_as_uint(dk);
                const unsigned key32 = (u & 0x80000000u) ? ~u : (u | 0x80000000u);
                const unsigned long long key =
                    ((unsigned long long)key32 << 32) | (unsigned)k;
                atomicMin(&s_res[row], key);   // min dk, tie -> min k == np.argmin
            }
        }
    }
    __syncthreads();

    // --- output: wave wid writes rows wid*4..+3 (coalesced 256B each) --------
    const size_t n0 = (size_t)gw * 64 + w0;
#pragma unroll 1
    for (int rr = 0; rr < 4; ++rr) {
        const int row = wid * 4 + rr;
        const int bi  = (int)(s_res[row] & 0xFFFFFFFFull);
        out[(n0 + row) * CODE_DIM + lane] = cb[(size_t)bi * CODE_DIM + lane];
    }
}

// ---------------- fallback (R9, proven 190us) if ws too small ---------------
__device__ __forceinline__ float exact_dk_fb(const float* __restrict__ cb,
                                             const float* __restrict__ c2,
                                             const float (&x)[CODE_DIM], float x2, int k) {
    const float* crow = cb + (size_t)k * CODE_DIM;
    double a0 = 0.0, a1 = 0.0, a2 = 0.0, a3 = 0.0;
#pragma unroll
    for (int j = 0; j < CODE_DIM; j += 4) {
        a0 = fma((double)crow[j + 0], (double)x[j + 0], a0);
        a1 = fma((double)crow[j + 1], (double)x[j + 1], a1);
        a2 = fma((double)crow[j + 2], (double)x[j + 2], a2);
        a3 = fma((double)crow[j + 3], (double)x[j + 3], a3);
    }
    const double dot = (a0 + a1) + (a2 + a3);
    const float  ein = (float)dot;
    return __fsub_rn(__fadd_rn(x2, c2[k]), __fmul_rn(2.0f, ein));
}

__global__ __launch_bounds__(512, 2)
void vq_fallback_kernel(const float* __restrict__ in, const float* __restrict__ cb,
                        const float* __restrict__ c2, float* __restrict__ out) {
    __shared__ float s_rb[8][64];
    __shared__ int   s_ri[8][64];
    const int tid = threadIdx.x, lane = tid & 63, wid = tid >> 6;
    const int gw = blockIdx.x, b = gw >> 6, h = gw & 63;
    const float* xin = in + (size_t)b * B_STRIDE + (size_t)h * 64 + lane;
    float x[CODE_DIM];
#pragma unroll
    for (int c = 0; c < CODE_DIM; ++c) x[c] = xin[(size_t)c * CH_STRIDE];
    float r[8];
#pragma unroll
    for (int j = 0; j < 8; ++j) r[j] = __fmul_rn(x[j], x[j]);
#pragma unroll
    for (int i = 8; i < 64; i += 8)
#pragma unroll
        for (int j = 0; j < 8; ++j) r[j] = __fadd_rn(r[j], __fmul_rn(x[i + j], x[i + j]));
    const float x2 = __fadd_rn(__fadd_rn(__fadd_rn(r[0], r[1]), __fadd_rn(r[2], r[3])),
                               __fadd_rn(__fadd_rn(r[4], r[5]), __fadd_rn(r[6], r[7])));
    const int k0 = __builtin_amdgcn_readfirstlane(wid) * 64;
    float ex_best = INFINITY; int bi = k0;
#pragma unroll 1
    for (int kk = 0; kk < 64; ++kk) {
        const float dk = exact_dk_fb(cb, c2, x, x2, k0 + kk);
        if (dk < ex_best) { ex_best = dk; bi = k0 + kk; }
    }
    s_rb[wid][lane] = ex_best; s_ri[wid][lane] = bi;
    __syncthreads();
    float fb2 = s_rb[0][lane]; int fi = s_ri[0][lane];
#pragma unroll
    for (int w = 1; w < 8; ++w) {
        if (s_rb[w][lane] < fb2) { fb2 = s_rb[w][lane]; fi = s_ri[w][lane]; }
    }
    const size_t n0 = (size_t)gw * 64;
#pragma unroll 1
    for (int rr = 0; rr < 8; ++rr) {
        const int row = wid * 8 + rr;
        const int idxr = __shfl(fi, row, 64);
        out[(n0 + row) * CODE_DIM + lane] = cb[(size_t)idxr * CODE_DIM + lane];
    }
}

extern "C" void kernel_launch(void* const* d_in, const int* in_sizes, int n_in,
                              void* d_out, int out_size, void* d_ws, size_t ws_size,
                              hipStream_t stream) {
    const float* in  = (const float*)d_in[0];   // (16,64,64,64) fp32
    const float* cb  = (const float*)d_in[1];   // (512,64) fp32
    float*       out = (float*)d_out;           // (16,64,64,64) fp32

    float* c2  = (float*)d_ws;                              // 2 KB
    float* cbT = (float*)((char*)d_ws + 2048);              // 128 KB
    const bool hasT = ws_size >= (size_t)(2048 + N_CODES * CODE_DIM * 4);

    vq_setup_kernel<<<dim3(64), dim3(512), 0, stream>>>(cb, c2, hasT ? cbT : c2,
                                                        hasT ? 1 : 0);
    if (hasT) {
        // 4096 blocks = 1024 (b,h) groups x 4 row-quarters; 256 threads.
        vq_gemm_kernel<<<dim3(4096), dim3(256), 0, stream>>>(in, cb, c2, cbT, out);
    } else {
        vq_fallback_kernel<<<dim3(1024), dim3(512), 0, stream>>>(in, cb, c2, out);
    }
}

// Round 12
// 178.652 us; speedup vs baseline: 2.0627x; 1.2921x over previous
//
#include <hip/hip_runtime.h>
#include <math.h>

// VectorQuantizer — bit-exact emulation of the numpy fp32 reference (proven R2-R11):
//   d[n,k] = fl32( fl32(x2[n]+c2[k]) - fl32(2 * fl32(exact_fp64_dot)) ), first argmin.
// R11's GEMM tiling (16 rows x 512 codes per block, 4x8 lane tile, cbT[dim][code]
// L2-resident) is the right structure, but its resolve loops used `unroll 1`, so
// acc[r][j] was runtime-indexed -> the whole accumulator array was demoted to
// scratch (VGPR=52, 277MB scratch writes @2TB/s). R12: fully-unrolled filter
// (compile-time acc indices) + __noinline__ fp64 resolver (runtime row/k touch
// only LDS/global). acc stays in 32 VGPRs; scratch traffic gone.

#define N_CODES   512
#define CODE_DIM  64
#define CH_STRIDE 4096                      // floats between channels
#define B_STRIDE  (CODE_DIM * CH_STRIDE)    // floats between batches
#define RPB       16                        // rows per block
#define XPITCH    20                        // xs pitch (mult of 4 -> b128-aligned)
#define THR       1.2e-4f                   // >= 2*(dk-formula rounding + fast-dot err)

// ---------------- setup: c2 (numpy pairwise) + cbT transpose ----------------
__device__ __forceinline__ float np_pairwise_sum64(const float* a) {
    float r[8];
#pragma unroll
    for (int j = 0; j < 8; ++j) r[j] = a[j];
#pragma unroll
    for (int i = 8; i < 64; i += 8) {
#pragma unroll
        for (int j = 0; j < 8; ++j) r[j] = __fadd_rn(r[j], a[i + j]);
    }
    return __fadd_rn(__fadd_rn(__fadd_rn(r[0], r[1]), __fadd_rn(r[2], r[3])),
                     __fadd_rn(__fadd_rn(r[4], r[5]), __fadd_rn(r[6], r[7])));
}

__global__ void vq_setup_kernel(const float* __restrict__ cb, float* __restrict__ c2,
                                float* __restrict__ cbT, int buildT) {
    const int t = blockIdx.x * blockDim.x + threadIdx.x;   // 64 blocks x 512
    if (buildT && t < N_CODES * CODE_DIM) {
        const int j = t >> 9, k = t & 511;                 // cbT[j][k] = cb[k][j]
        cbT[(j << 9) | k] = cb[k * CODE_DIM + j];
    }
    if (t < N_CODES) {
        const float* row = cb + t * CODE_DIM;
        float sq[CODE_DIM];
#pragma unroll
        for (int j = 0; j < CODE_DIM; ++j) sq[j] = __fmul_rn(row[j], row[j]);
        c2[t] = np_pairwise_sum64(sq);
    }
}

// Rare-path exact resolver (bit-identical R2 arithmetic). __noinline__: one code
// copy; args are runtime but it touches only LDS (xs,x2e,res) and global (cb,c2)
// — no register arrays, so the caller's acc[] stays in VGPRs.
__device__ __noinline__ void resolve_cell(const float* __restrict__ cb,
                                          const float* __restrict__ c2g,
                                          const float* xs_base,      // &xs[0][0]
                                          const float* s_x2e,
                                          unsigned long long* s_res,
                                          int row, int k) {
    const float* crow = cb + (size_t)k * CODE_DIM;
    double b0 = 0.0, b1 = 0.0, b2 = 0.0, b3 = 0.0;
#pragma unroll
    for (int c = 0; c < CODE_DIM; c += 4) {
        b0 = fma((double)crow[c + 0], (double)xs_base[(c + 0) * XPITCH + row], b0);
        b1 = fma((double)crow[c + 1], (double)xs_base[(c + 1) * XPITCH + row], b1);
        b2 = fma((double)crow[c + 2], (double)xs_base[(c + 2) * XPITCH + row], b2);
        b3 = fma((double)crow[c + 3], (double)xs_base[(c + 3) * XPITCH + row], b3);
    }
    const double dot64 = (b0 + b1) + (b2 + b3);
    const float  ein   = (float)dot64;
    const float  tmp   = __fadd_rn(s_x2e[row], c2g[k]);
    const float  dk    = __fsub_rn(tmp, __fmul_rn(2.0f, ein));
    const unsigned u     = __float_as_uint(dk);
    const unsigned key32 = (u & 0x80000000u) ? ~u : (u | 0x80000000u);
    atomicMin(&s_res[row], ((unsigned long long)key32 << 32) | (unsigned)k);
}

// ---------------- main: GEMM-tiled scan + exact resolve ---------------------
__global__ __launch_bounds__(256)
void vq_gemm_kernel(const float* __restrict__ in,
                    const float* __restrict__ cb,
                    const float* __restrict__ c2g,
                    const float* __restrict__ cbT,
                    float* __restrict__ out) {
    __shared__ __align__(16) float xs[CODE_DIM][XPITCH];   // x-tile [dim][row], 5KB
    __shared__ float s_wm[4][RPB];                         // per-wave row mins
    __shared__ float s_bmin[RPB];
    __shared__ float s_x2e[RPB];                           // numpy-exact x2 per row
    __shared__ unsigned long long s_res[RPB];              // packed (dk-key, k)

    const int tid  = threadIdx.x;
    const int lane = tid & 63;
    const int wid  = tid >> 6;              // 0..3
    const int gw   = blockIdx.x >> 2;       // (b,h) group 0..1023
    const int w0   = (blockIdx.x & 3) * RPB;

    const float* src = in + (size_t)(gw >> 6) * B_STRIDE + (size_t)(gw & 63) * 64;

    // --- stage x-tile: xs[c][r] = src[c*4096 + w0 + r]; 4 values per thread ---
    {
        const int r  = tid & 15;
        const int c0 = (tid >> 4) * 4;
#pragma unroll
        for (int i = 0; i < 4; ++i)
            xs[c0 + i][r] = src[(size_t)(c0 + i) * CH_STRIDE + w0 + r];
    }
    if (tid < RPB) s_res[tid] = ~0ull;
    __syncthreads();

    // --- numpy-exact x2 per row (R5-proven rolling 8-acc pairwise order) -----
    if (tid < RPB) {
        float r[8];
#pragma unroll
        for (int j = 0; j < 8; ++j) r[j] = __fmul_rn(xs[j][tid], xs[j][tid]);
#pragma unroll
        for (int i = 8; i < 64; i += 8) {
#pragma unroll
            for (int j = 0; j < 8; ++j)
                r[j] = __fadd_rn(r[j], __fmul_rn(xs[i + j][tid], xs[i + j][tid]));
        }
        s_x2e[tid] = __fadd_rn(
            __fadd_rn(__fadd_rn(r[0], r[1]), __fadd_rn(r[2], r[3])),
            __fadd_rn(__fadd_rn(r[4], r[5]), __fadd_rn(r[6], r[7])));
    }

    // --- lane tile: rows r0..r0+3, codes code0..code0+7 ----------------------
    const int r0    = (lane & 3) * 4;
    const int code0 = wid * 128 + (lane >> 2) * 8;

    float acc[4][8];
#pragma unroll
    for (int r = 0; r < 4; ++r)
#pragma unroll
        for (int j = 0; j < 8; ++j) acc[r][j] = 0.f;

    // --- hot loop: per dim 1 LDS b128 + 2 coalesced global dwordx4 -> 32 FMA --
    const float* cbTw = cbT + code0;
#pragma unroll 4
    for (int c = 0; c < CODE_DIM; ++c) {
        const float4 xv  = *(const float4*)&xs[c][r0];
        const float4 ca  = *(const float4*)(cbTw + (size_t)c * N_CODES);
        const float4 cb4 = *(const float4*)(cbTw + (size_t)c * N_CODES + 4);
        const float xr[4] = {xv.x, xv.y, xv.z, xv.w};
        const float cv[8] = {ca.x, ca.y, ca.z, ca.w, cb4.x, cb4.y, cb4.z, cb4.w};
#pragma unroll
        for (int r = 0; r < 4; ++r)
#pragma unroll
            for (int j = 0; j < 8; ++j)
                acc[r][j] = fmaf(xr[r], cv[j], acc[r][j]);
    }

    // ek = c2[k] - 2*dot  (x2 shift is argmin-invariant within a row)
    float c2v[8];
    {
        const float4 a = *(const float4*)(c2g + code0);
        const float4 b = *(const float4*)(c2g + code0 + 4);
        c2v[0] = a.x; c2v[1] = a.y; c2v[2] = a.z; c2v[3] = a.w;
        c2v[4] = b.x; c2v[5] = b.y; c2v[6] = b.z; c2v[7] = b.w;
    }
#pragma unroll
    for (int r = 0; r < 4; ++r)
#pragma unroll
        for (int j = 0; j < 8; ++j)
            acc[r][j] = __fmaf_rn(-2.0f, acc[r][j], c2v[j]);

    // --- per-row fast min: lane tile -> shuffle over lanes sharing row-group --
    float m[4];
#pragma unroll
    for (int r = 0; r < 4; ++r) {
        float mm = acc[r][0];
#pragma unroll
        for (int j = 1; j < 8; ++j) mm = fminf(mm, acc[r][j]);
        m[r] = mm;
    }
#pragma unroll
    for (int s = 4; s < 64; s <<= 1) {
#pragma unroll
        for (int r = 0; r < 4; ++r) m[r] = fminf(m[r], __shfl_xor(m[r], s, 64));
    }
    if (lane < 4) {
#pragma unroll
        for (int r = 0; r < 4; ++r) s_wm[wid][lane * 4 + r] = m[r];
    }
    __syncthreads();
    if (tid < RPB) {
        float bm = s_wm[0][tid];
#pragma unroll
        for (int w = 1; w < 4; ++w) bm = fminf(bm, s_wm[w][tid]);
        s_bmin[tid] = bm;
    }
    __syncthreads();

    // --- filter (FULLY unrolled: acc indices compile-time) + rare resolve ----
#pragma unroll
    for (int r = 0; r < 4; ++r) {
#pragma unroll
        for (int j = 0; j < 8; ++j) {
            if (acc[r][j] <= s_bmin[r0 + r] + THR)
                resolve_cell(cb, c2g, &xs[0][0], s_x2e, s_res, r0 + r, code0 + j);
        }
    }
    __syncthreads();

    // --- output: wave wid writes rows wid*4..+3 (coalesced 256B each) --------
    const size_t n0 = (size_t)gw * 64 + w0;
#pragma unroll
    for (int rr = 0; rr < 4; ++rr) {
        const int row = wid * 4 + rr;
        const int bi  = (int)(s_res[row] & 0xFFFFFFFFull);
        out[(n0 + row) * CODE_DIM + lane] = cb[(size_t)bi * CODE_DIM + lane];
    }
}

// ---------------- fallback (R9, proven 190us) if ws too small ---------------
__device__ __forceinline__ float exact_dk_fb(const float* __restrict__ cb,
                                             const float* __restrict__ c2,
                                             const float (&x)[CODE_DIM], float x2, int k) {
    const float* crow = cb + (size_t)k * CODE_DIM;
    double a0 = 0.0, a1 = 0.0, a2 = 0.0, a3 = 0.0;
#pragma unroll
    for (int j = 0; j < CODE_DIM; j += 4) {
        a0 = fma((double)crow[j + 0], (double)x[j + 0], a0);
        a1 = fma((double)crow[j + 1], (double)x[j + 1], a1);
        a2 = fma((double)crow[j + 2], (double)x[j + 2], a2);
        a3 = fma((double)crow[j + 3], (double)x[j + 3], a3);
    }
    const double dot = (a0 + a1) + (a2 + a3);
    const float  ein = (float)dot;
    return __fsub_rn(__fadd_rn(x2, c2[k]), __fmul_rn(2.0f, ein));
}

__global__ __launch_bounds__(512, 2)
void vq_fallback_kernel(const float* __restrict__ in, const float* __restrict__ cb,
                        const float* __restrict__ c2, float* __restrict__ out) {
    __shared__ float s_rb[8][64];
    __shared__ int   s_ri[8][64];
    const int tid = threadIdx.x, lane = tid & 63, wid = tid >> 6;
    const int gw = blockIdx.x, b = gw >> 6, h = gw & 63;
    const float* xin = in + (size_t)b * B_STRIDE + (size_t)h * 64 + lane;
    float x[CODE_DIM];
#pragma unroll
    for (int c = 0; c < CODE_DIM; ++c) x[c] = xin[(size_t)c * CH_STRIDE];
    float r[8];
#pragma unroll
    for (int j = 0; j < 8; ++j) r[j] = __fmul_rn(x[j], x[j]);
#pragma unroll
    for (int i = 8; i < 64; i += 8)
#pragma unroll
        for (int j = 0; j < 8; ++j) r[j] = __fadd_rn(r[j], __fmul_rn(x[i + j], x[i + j]));
    const float x2 = __fadd_rn(__fadd_rn(__fadd_rn(r[0], r[1]), __fadd_rn(r[2], r[3])),
                               __fadd_rn(__fadd_rn(r[4], r[5]), __fadd_rn(r[6], r[7])));
    const int k0 = __builtin_amdgcn_readfirstlane(wid) * 64;
    float ex_best = INFINITY; int bi = k0;
#pragma unroll 1
    for (int kk = 0; kk < 64; ++kk) {
        const float dk = exact_dk_fb(cb, c2, x, x2, k0 + kk);
        if (dk < ex_best) { ex_best = dk; bi = k0 + kk; }
    }
    s_rb[wid][lane] = ex_best; s_ri[wid][lane] = bi;
    __syncthreads();
    float fb2 = s_rb[0][lane]; int fi = s_ri[0][lane];
#pragma unroll
    for (int w = 1; w < 8; ++w) {
        if (s_rb[w][lane] < fb2) { fb2 = s_rb[w][lane]; fi = s_ri[w][lane]; }
    }
    const size_t n0 = (size_t)gw * 64;
#pragma unroll 1
    for (int rr = 0; rr < 8; ++rr) {
        const int row = wid * 8 + rr;
        const int idxr = __shfl(fi, row, 64);
        out[(n0 + row) * CODE_DIM + lane] = cb[(size_t)idxr * CODE_DIM + lane];
    }
}

extern "C" void kernel_launch(void* const* d_in, const int* in_sizes, int n_in,
                              void* d_out, int out_size, void* d_ws, size_t ws_size,
                              hipStream_t stream) {
    const float* in  = (const float*)d_in[0];   // (16,64,64,64) fp32
    const float* cb  = (const float*)d_in[1];   // (512,64) fp32
    float*       out = (float*)d_out;           // (16,64,64,64) fp32

    float* c2  = (float*)d_ws;                              // 2 KB
    float* cbT = (float*)((char*)d_ws + 2048);              // 128 KB
    const bool hasT = ws_size >= (size_t)(2048 + N_CODES * CODE_DIM * 4);

    vq_setup_kernel<<<dim3(64), dim3(512), 0, stream>>>(cb, c2, hasT ? cbT : c2,
                                                        hasT ? 1 : 0);
    if (hasT) {
        // 4096 blocks = 1024 (b,h) groups x 4 row-quarters; 256 threads.
        vq_gemm_kernel<<<dim3(4096), dim3(256), 0, stream>>>(in, cb, c2, cbT, out);
    } else {
        vq_fallback_kernel<<<dim3(1024), dim3(512), 0, stream>>>(in, cb, c2, out);
    }
}